// Round 6
// baseline (66.712 us; speedup 1.0000x reference)
//
#include <hip/hip_runtime.h>
#include <hip/hip_bf16.h>
#include <math.h>

#define F_DIM 2048
#define B_DIM 4096
#define C_DIM 100
#define D_DIM 16
#define N_DIM (C_DIM*D_DIM)   // 1600
#define N_PAD 1664            // 13 tiles of 128
#define RIDGE_EPS 1e-4f

typedef __attribute__((ext_vector_type(8))) short bf16x8;
typedef __attribute__((ext_vector_type(4))) float f32x4;
typedef __attribute__((ext_vector_type(2))) unsigned int u32x2;

__device__ __forceinline__ void gload16(const void* g, void* l) {
  __builtin_amdgcn_global_load_lds(
      (const __attribute__((address_space(1))) void*)g,
      (__attribute__((address_space(3))) void*)l,
      16, 0, 0);
}

#define FULL_BAR() asm volatile("s_waitcnt vmcnt(0) lgkmcnt(0)\n\ts_barrier" ::: "memory")

__device__ __forceinline__ unsigned short f2bf(float f) {
  unsigned u = __float_as_uint(f);
  u += 0x7FFFu + ((u >> 16) & 1u);
  return (unsigned short)(u >> 16);
}

// ---- fused: blocks 0..99 = per-capsule Gram+inverse (reads fp32 w directly);
//      blocks 100.. = fp32->bf16 convert of w + zero-pad of wb rows ----
__global__ __launch_bounds__(256) void cvt_gram_kernel(
    const float* __restrict__ w, unsigned short* __restrict__ wb,
    float* __restrict__ sigma, int nw8, int npad8) {
  __shared__ float part[4][64][4];
  __shared__ float G[16][17];
  __shared__ float IV[16][17];
  int t = threadIdx.x;
  if (blockIdx.x < C_DIM) {
    // ---------------- gram + Gauss-Jordan inverse ----------------
    int c = blockIdx.x;
    int lane = t & 63, wid = t >> 6;
    const float* src = w + (size_t)c * (D_DIM * F_DIM)
                         + (size_t)(lane & 15) * F_DIM + ((lane >> 4) * 8) + wid * 512;
    f32x4 g = {0.f, 0.f, 0.f, 0.f};
#pragma unroll
    for (int kt = 0; kt < 16; ++kt) {
      float4 v0 = *(const float4*)(src + kt * 32);
      float4 v1 = *(const float4*)(src + kt * 32 + 4);
      bf16x8 f;
      f[0] = (short)f2bf(v0.x); f[1] = (short)f2bf(v0.y);
      f[2] = (short)f2bf(v0.z); f[3] = (short)f2bf(v0.w);
      f[4] = (short)f2bf(v1.x); f[5] = (short)f2bf(v1.y);
      f[6] = (short)f2bf(v1.z); f[7] = (short)f2bf(v1.w);
      g = __builtin_amdgcn_mfma_f32_16x16x32_bf16(f, f, g, 0, 0, 0);
    }
#pragma unroll
    for (int j = 0; j < 4; j++) part[wid][lane][j] = g[j];
    int d = t >> 4, e = t & 15;
    IV[d][e] = (d == e) ? 1.f : 0.f;
    __syncthreads();
    if (t < 64) {
      int col = t & 15;
#pragma unroll
      for (int j = 0; j < 4; j++) {
        int row = (t >> 4) * 4 + j;   // C/D layout; G symmetric so transpose harmless
        float s4 = part[0][t][j] + part[1][t][j] + part[2][t][j] + part[3][t][j];
        G[row][col] = s4 + (row == col ? RIDGE_EPS : 0.f);
      }
    }
    __syncthreads();
    for (int k = 0; k < 16; k++) {
      float piv = G[k][k];
      float gke = G[k][e];
      float ike = IV[k][e];
      float f   = G[d][k];
      float gde = G[d][e];
      float ide = IV[d][e];
      __syncthreads();
      if (d == k) {
        G[k][e]  = gke / piv;
        IV[k][e] = ike / piv;
      } else {
        G[d][e]  = gde - f * gke / piv;
        IV[d][e] = ide - f * ike / piv;
      }
      __syncthreads();
    }
    sigma[(size_t)c * 256 + t] = IV[d][e];
    return;
  }
  // ---------------- w convert + pad ----------------
  int idx = (blockIdx.x - C_DIM) * 256 + t;
  if (idx >= nw8) {
    int idx3 = idx - nw8;
    if (idx3 < npad8) {  // zero-fill wb pad rows 1600..1663
      uint4 z = {0, 0, 0, 0};
      *((uint4*)(wb + (size_t)N_DIM * F_DIM) + idx3) = z;
    }
    return;
  }
  const float4* p = (const float4*)w + (size_t)idx * 2;
  float4 a = p[0], b = p[1];
  float v[8] = {a.x, a.y, a.z, a.w, b.x, b.y, b.z, b.w};
  union { unsigned short u16[8]; uint4 u4; } r;
#pragma unroll
  for (int j = 0; j < 8; j++) r.u16[j] = f2bf(v[j]);
  *((uint4*)wb + idx) = r.u4;
}

// ------------- fused bf16 MFMA GEMM (u = x W^T) + sqrt(u^T S u) -------------
// tile BM=128 x BN=128 (8 capsules), BK=64, 4 waves 2x2, each 64x64 (4x4 frags)
// A staged from fp32 x via reg+convert+swizzled ds_write (no pre-convert pass);
// B via global_load_lds from pre-converted wb. ONE barrier per K-step:
//   { loadA_reg(t+1); loadB_lds(t+1,nxt); compute(cur); cvt+writeA(nxt); bar }
// writes target the buffer whose readers were barriered one iteration ago.
__global__ __launch_bounds__(256) void gemm_caps_kernel(
    const float* __restrict__ x,             // [4096][2048] fp32
    const unsigned short* __restrict__ wb,   // [1664][2048] bf16 (rows>=1600 zero)
    const float* __restrict__ sigma,         // [100][16][16]
    float* __restrict__ out)                 // [4096][100]
{
  __shared__ __align__(16) unsigned char smem[65536];
  const int t = threadIdx.x;
  const int lane = t & 63;
  const int wid = t >> 6;
  const int wr = wid >> 1, wc = wid & 1;    // 2x2 wave grid
  // bijective XCD swizzle: 416 blocks = 8 XCDs x 52
  const int bid = blockIdx.x;
  const int swz = (bid & 7) * 52 + (bid >> 3);
  const int bn = swz % 13;          // 13 consecutive share the A panel
  const int bm = swz / 13;
  const int rowBase = bm * 128;
  const int colBase = bn * 128;

  unsigned char* buf0 = smem;
  unsigned char* buf1 = smem + 32768;
  // per-buffer: sA = buf (128x64 bf16 = 16KB), sB = buf+16384 (128x64 = 16KB)

  // ---- A staging: 8 float4 loads/wave from fp32 x (rows wid*32..+31) ----
  const float* aSrc = x + (size_t)(rowBase + wid * 32 + (lane >> 4)) * F_DIM + (lane & 15) * 4;
  int wOffA[8];
#pragma unroll
  for (int i = 0; i < 8; i++) {
    int r = wid * 32 + i * 4 + (lane >> 4);
    wOffA[i] = r * 128 + (((lane & 15) * 8) ^ ((r & 7) << 4));  // swizzled ds_write addr
  }
  // ---- B staging: 4 gload_lds of 1KB, source pre-swizzled (m173) ----
  const unsigned short* srcB[4]; unsigned qB[4];
#pragma unroll
  for (int i = 0; i < 4; i++) {
    unsigned q = (unsigned)wid * 4096u + (unsigned)i * 1024u + (unsigned)lane * 16u;
    unsigned r = q >> 7, b = q & 127u;
    unsigned cb = b ^ ((r & 7u) << 4);          // inverse swizzle on source
    qB[i] = 16384u + q;
    srcB[i] = wb + (size_t)(colBase + (int)r) * F_DIM + (cb >> 1);
  }

  // swizzled ds_read byte offsets (relative to buffer base)
  int aOff[4][2], bOff[4][2];
#pragma unroll
  for (int m = 0; m < 4; m++) {
    int r = wr * 64 + m * 16 + (lane & 15);
    int sw = (r & 7) << 4;
#pragma unroll
    for (int ks = 0; ks < 2; ks++) {
      int kb = ks * 64 + ((lane >> 4) << 4);
      aOff[m][ks] = r * 128 + (kb ^ sw);
    }
  }
#pragma unroll
  for (int n = 0; n < 4; n++) {
    int r = wc * 64 + n * 16 + (lane & 15);
    int sw = (r & 7) << 4;
#pragma unroll
    for (int ks = 0; ks < 2; ks++) {
      int kb = ks * 64 + ((lane >> 4) << 4);
      bOff[n][ks] = 16384 + r * 128 + (kb ^ sw);
    }
  }

  f32x4 acc[4][4];
#pragma unroll
  for (int m = 0; m < 4; m++)
#pragma unroll
    for (int n = 0; n < 4; n++)
      acc[m][n] = (f32x4){0.f, 0.f, 0.f, 0.f};

  f32x4 areg[8];
  auto loadA = [&](int kt) {
#pragma unroll
    for (int i = 0; i < 8; i++)
      areg[i] = *(const f32x4*)(aSrc + (size_t)i * 4 * F_DIM + kt * 64);
  };
  auto loadB = [&](unsigned char* buf, int kt) {
    const size_t koff = (size_t)kt * 64;
#pragma unroll
    for (int i = 0; i < 4; i++) gload16(srcB[i] + koff, buf + qB[i]);
  };
  auto writeA = [&](unsigned char* buf) {
#pragma unroll
    for (int i = 0; i < 8; i++) {
      unsigned lo = ((unsigned)f2bf(areg[i][1]) << 16) | f2bf(areg[i][0]);
      unsigned hi = ((unsigned)f2bf(areg[i][3]) << 16) | f2bf(areg[i][2]);
      u32x2 v; v[0] = lo; v[1] = hi;
      *(u32x2*)(buf + wOffA[i]) = v;
    }
  };
  auto compute = [&](const unsigned char* buf) {
#pragma unroll
    for (int ks = 0; ks < 2; ks++) {
      bf16x8 a0 = *(const bf16x8*)(buf + aOff[0][ks]);
      bf16x8 a1 = *(const bf16x8*)(buf + aOff[1][ks]);
      bf16x8 a2 = *(const bf16x8*)(buf + aOff[2][ks]);
      bf16x8 a3 = *(const bf16x8*)(buf + aOff[3][ks]);
      bf16x8 b0 = *(const bf16x8*)(buf + bOff[0][ks]);
      bf16x8 b1 = *(const bf16x8*)(buf + bOff[1][ks]);
      bf16x8 b2 = *(const bf16x8*)(buf + bOff[2][ks]);
      bf16x8 b3 = *(const bf16x8*)(buf + bOff[3][ks]);
      __builtin_amdgcn_s_setprio(1);
      acc[0][0] = __builtin_amdgcn_mfma_f32_16x16x32_bf16(a0, b0, acc[0][0], 0, 0, 0);
      acc[0][1] = __builtin_amdgcn_mfma_f32_16x16x32_bf16(a0, b1, acc[0][1], 0, 0, 0);
      acc[0][2] = __builtin_amdgcn_mfma_f32_16x16x32_bf16(a0, b2, acc[0][2], 0, 0, 0);
      acc[0][3] = __builtin_amdgcn_mfma_f32_16x16x32_bf16(a0, b3, acc[0][3], 0, 0, 0);
      acc[1][0] = __builtin_amdgcn_mfma_f32_16x16x32_bf16(a1, b0, acc[1][0], 0, 0, 0);
      acc[1][1] = __builtin_amdgcn_mfma_f32_16x16x32_bf16(a1, b1, acc[1][1], 0, 0, 0);
      acc[1][2] = __builtin_amdgcn_mfma_f32_16x16x32_bf16(a1, b2, acc[1][2], 0, 0, 0);
      acc[1][3] = __builtin_amdgcn_mfma_f32_16x16x32_bf16(a1, b3, acc[1][3], 0, 0, 0);
      acc[2][0] = __builtin_amdgcn_mfma_f32_16x16x32_bf16(a2, b0, acc[2][0], 0, 0, 0);
      acc[2][1] = __builtin_amdgcn_mfma_f32_16x16x32_bf16(a2, b1, acc[2][1], 0, 0, 0);
      acc[2][2] = __builtin_amdgcn_mfma_f32_16x16x32_bf16(a2, b2, acc[2][2], 0, 0, 0);
      acc[2][3] = __builtin_amdgcn_mfma_f32_16x16x32_bf16(a2, b3, acc[2][3], 0, 0, 0);
      acc[3][0] = __builtin_amdgcn_mfma_f32_16x16x32_bf16(a3, b0, acc[3][0], 0, 0, 0);
      acc[3][1] = __builtin_amdgcn_mfma_f32_16x16x32_bf16(a3, b1, acc[3][1], 0, 0, 0);
      acc[3][2] = __builtin_amdgcn_mfma_f32_16x16x32_bf16(a3, b2, acc[3][2], 0, 0, 0);
      acc[3][3] = __builtin_amdgcn_mfma_f32_16x16x32_bf16(a3, b3, acc[3][3], 0, 0, 0);
      __builtin_amdgcn_s_setprio(0);
    }
  };

  // prologue: tile 0 -> buf0
  loadA(0);
  loadB(buf0, 0);
  writeA(buf0);          // compiler inserts vmcnt waits for areg uses
  FULL_BAR();
  // main loop: one barrier per K-step; stage t+1 overlaps compute t
  for (int kt = 0; kt < 30; kt += 2) {
    loadA(kt + 1);
    loadB(buf1, kt + 1);
    compute(buf0);
    __builtin_amdgcn_sched_barrier(0);
    writeA(buf1);
    FULL_BAR();
    loadA(kt + 2);
    loadB(buf0, kt + 2);
    compute(buf1);
    __builtin_amdgcn_sched_barrier(0);
    writeA(buf0);
    FULL_BAR();
  }
  loadA(31);
  loadB(buf1, 31);
  compute(buf0);
  __builtin_amdgcn_sched_barrier(0);
  writeA(buf1);
  FULL_BAR();
  compute(buf1);
  asm volatile("s_waitcnt lgkmcnt(0)\n\ts_barrier" ::: "memory");  // reads done before smem reuse

  // ---- epilogue: u -> LDS [128][128] with conflict-free XOR-granule swizzle
  // g = (col>>2) ^ (row&3) ^ ((row>>2)&7): distinct across the C-write's mod-4
  // row groups AND across consecutive rows on the read side -> 2 lanes/bank.
  float* uT = (float*)smem;
#pragma unroll
  for (int m = 0; m < 4; m++)
#pragma unroll
    for (int n = 0; n < 4; n++)
#pragma unroll
      for (int j = 0; j < 4; j++) {
        int row = wr * 64 + m * 16 + ((lane >> 4) << 2) + j;  // C/D layout
        int col = wc * 64 + n * 16 + (lane & 15);
        int g = (col >> 2) ^ (row & 3) ^ ((row >> 2) & 7);
        uT[row * 128 + g * 4 + (col & 3)] = acc[m][n][j];
      }
  __syncthreads();
  const int capBase = bn * 8;
#pragma unroll
  for (int pp = 0; pp < 4; ++pp) {
    int pi = t + pp * 256;
    int row = pi & 127;
    int cl = __builtin_amdgcn_readfirstlane(pi >> 7);  // wave-uniform capsule
    float ur[16];
#pragma unroll
    for (int q = 0; q < 4; q++) {
      int g = (cl * 4 + q) ^ (row & 3) ^ ((row >> 2) & 7);
      f32x4 v = *(const f32x4*)(uT + row * 128 + g * 4);
#pragma unroll
      for (int j = 0; j < 4; j++) ur[q * 4 + j] = v[j];
    }
    int cap = capBase + cl;
    const float* s = sigma + (size_t)cap * 256;   // wave-uniform -> s_loads
    float qf = 0.f;
#pragma unroll
    for (int dd = 0; dd < 16; ++dd) {
      float td = 0.f;
#pragma unroll
      for (int ee = 0; ee < 16; ++ee) td = fmaf(s[dd * 16 + ee], ur[ee], td);
      qf = fmaf(ur[dd], td, qf);
    }
    if (cap < C_DIM)
      out[(size_t)(rowBase + row) * C_DIM + cap] = sqrtf(fmaxf(qf, 0.f));
  }
}

extern "C" void kernel_launch(void* const* d_in, const int* in_sizes, int n_in,
                              void* d_out, int out_size, void* d_ws, size_t ws_size,
                              hipStream_t stream) {
  const float* x = (const float*)d_in[0];   // [4096][2048]
  const float* w = (const float*)d_in[1];   // [100][16][2048]
  float* out = (float*)d_out;               // [4096][100]

  unsigned short* wb = (unsigned short*)d_ws;              // 1664 rows bf16 = 6.8 MB
  float* sigma = (float*)(wb + (size_t)N_PAD * F_DIM);     // 100x256 f32 (+pad caps read-only)

  int nw8 = N_DIM * F_DIM / 8;              // 409600
  int npad8 = (N_PAD - N_DIM) * F_DIM / 8;  // 16384
  int grid = C_DIM + (nw8 + npad8 + 255) / 256;   // gram blocks first, then w-convert
  cvt_gram_kernel<<<grid, 256, 0, stream>>>(w, wb, sigma, nw8, npad8);
  gemm_caps_kernel<<<(B_DIM / 128) * (N_PAD / 128), 256, 0, stream>>>(x, wb, sigma, out);
}

// Round 7
// 65.517 us; speedup vs baseline: 1.0182x; 1.0182x over previous
//
#include <hip/hip_runtime.h>
#include <hip/hip_bf16.h>
#include <math.h>

#define F_DIM 2048
#define B_DIM 4096
#define C_DIM 100
#define D_DIM 16
#define N_DIM (C_DIM*D_DIM)   // 1600
#define N_PAD 1664            // 13 tiles of 128
#define RIDGE_EPS 1e-4f

typedef __attribute__((ext_vector_type(8))) short bf16x8;
typedef __attribute__((ext_vector_type(4))) float f32x4;
typedef __attribute__((ext_vector_type(2))) unsigned int u32x2;

__device__ __forceinline__ void gload16(const void* g, void* l) {
  __builtin_amdgcn_global_load_lds(
      (const __attribute__((address_space(1))) void*)g,
      (__attribute__((address_space(3))) void*)l,
      16, 0, 0);
}

// counted-vmcnt barriers (T4): never drain to 0 in steady state.
#define BAR8()  asm volatile("s_waitcnt vmcnt(8) lgkmcnt(0)\n\ts_barrier" ::: "memory")
#define BAR0()  asm volatile("s_waitcnt vmcnt(0) lgkmcnt(0)\n\ts_barrier" ::: "memory")
#define BARLG() asm volatile("s_waitcnt lgkmcnt(0)\n\ts_barrier" ::: "memory")
#define SB0()   __builtin_amdgcn_sched_barrier(0)

__device__ __forceinline__ unsigned short f2bf(float f) {
  unsigned u = __float_as_uint(f);
  u += 0x7FFFu + ((u >> 16) & 1u);
  return (unsigned short)(u >> 16);
}

// ---- fused: blocks 0..99 = per-capsule Gram+inverse (reads fp32 w directly);
//      blocks 100.. = fp32->bf16 convert of w + zero-pad of wb rows ----
__global__ __launch_bounds__(256) void cvt_gram_kernel(
    const float* __restrict__ w, unsigned short* __restrict__ wb,
    float* __restrict__ sigma, int nw8, int npad8) {
  __shared__ float part[4][64][4];
  __shared__ float G[16][17];
  __shared__ float IV[16][17];
  int t = threadIdx.x;
  if (blockIdx.x < C_DIM) {
    int c = blockIdx.x;
    int lane = t & 63, wid = t >> 6;
    const float* src = w + (size_t)c * (D_DIM * F_DIM)
                         + (size_t)(lane & 15) * F_DIM + ((lane >> 4) * 8) + wid * 512;
    f32x4 g = {0.f, 0.f, 0.f, 0.f};
#pragma unroll
    for (int kt = 0; kt < 16; ++kt) {
      float4 v0 = *(const float4*)(src + kt * 32);
      float4 v1 = *(const float4*)(src + kt * 32 + 4);
      bf16x8 f;
      f[0] = (short)f2bf(v0.x); f[1] = (short)f2bf(v0.y);
      f[2] = (short)f2bf(v0.z); f[3] = (short)f2bf(v0.w);
      f[4] = (short)f2bf(v1.x); f[5] = (short)f2bf(v1.y);
      f[6] = (short)f2bf(v1.z); f[7] = (short)f2bf(v1.w);
      g = __builtin_amdgcn_mfma_f32_16x16x32_bf16(f, f, g, 0, 0, 0);
    }
#pragma unroll
    for (int j = 0; j < 4; j++) part[wid][lane][j] = g[j];
    int d = t >> 4, e = t & 15;
    IV[d][e] = (d == e) ? 1.f : 0.f;
    __syncthreads();
    if (t < 64) {
      int col = t & 15;
#pragma unroll
      for (int j = 0; j < 4; j++) {
        int row = (t >> 4) * 4 + j;   // C/D layout; G symmetric so transpose harmless
        float s4 = part[0][t][j] + part[1][t][j] + part[2][t][j] + part[3][t][j];
        G[row][col] = s4 + (row == col ? RIDGE_EPS : 0.f);
      }
    }
    __syncthreads();
    for (int k = 0; k < 16; k++) {
      float piv = G[k][k];
      float gke = G[k][e];
      float ike = IV[k][e];
      float f   = G[d][k];
      float gde = G[d][e];
      float ide = IV[d][e];
      __syncthreads();
      if (d == k) {
        G[k][e]  = gke / piv;
        IV[k][e] = ike / piv;
      } else {
        G[d][e]  = gde - f * gke / piv;
        IV[d][e] = ide - f * ike / piv;
      }
      __syncthreads();
    }
    sigma[(size_t)c * 256 + t] = IV[d][e];
    return;
  }
  int idx = (blockIdx.x - C_DIM) * 256 + t;
  if (idx >= nw8) {
    int idx3 = idx - nw8;
    if (idx3 < npad8) {
      uint4 z = {0, 0, 0, 0};
      *((uint4*)(wb + (size_t)N_DIM * F_DIM) + idx3) = z;
    }
    return;
  }
  const float4* p = (const float4*)w + (size_t)idx * 2;
  float4 a = p[0], b = p[1];
  float v[8] = {a.x, a.y, a.z, a.w, b.x, b.y, b.z, b.w};
  union { unsigned short u16[8]; uint4 u4; } r;
#pragma unroll
  for (int j = 0; j < 8; j++) r.u16[j] = f2bf(v[j]);
  *((uint4*)wb + idx) = r.u4;
}

// ------------- fused bf16 MFMA GEMM (u = x W^T) + sqrt(u^T S u) -------------
// BM=128 x BN=128, BK=64, 2x2 waves, 4x4 frags. A read as fp32 from x,
// converted in-reg, swizzled ds_write (2-deep reg pipeline: A(t+2) loaded at
// step t, written at step t+1). B via gload_lds from pre-converted wb.
// ONE barrier/K-step, counted vmcnt(8): A(t+2)'s 8 loads cross the barrier.
__global__ __launch_bounds__(256) void gemm_caps_kernel(
    const float* __restrict__ x,             // [4096][2048] fp32
    const unsigned short* __restrict__ wb,   // [1664][2048] bf16 (rows>=1600 zero)
    const float* __restrict__ sigma,         // [100][16][16]
    float* __restrict__ out)                 // [4096][100]
{
  __shared__ __align__(16) unsigned char smem[67584];
  const int t = threadIdx.x;
  const int lane = t & 63;
  const int wid = t >> 6;
  const int wr = wid >> 1, wc = wid & 1;    // 2x2 wave grid
  // bijective XCD swizzle: 416 blocks = 8 XCDs x 52
  const int bid = blockIdx.x;
  const int swz = (bid & 7) * 52 + (bid >> 3);
  const int bn = swz % 13;          // 13 consecutive share the A panel
  const int bm = swz / 13;
  const int rowBase = bm * 128;
  const int colBase = bn * 128;

  unsigned char* buf0 = smem;
  unsigned char* buf1 = smem + 32768;
  // per-buffer: sA = buf (128x64 bf16 = 16KB), sB = buf+16384 (128x64 = 16KB)

  // ---- A: 8 float4 loads/wave from fp32 x; swizzled b64 ds_writes ----
  const float* aSrc = x + (size_t)(rowBase + wid * 32 + (lane >> 4)) * F_DIM + (lane & 15) * 4;
  int wOffA[8];
#pragma unroll
  for (int i = 0; i < 8; i++) {
    int r = wid * 32 + i * 4 + (lane >> 4);
    wOffA[i] = r * 128 + (((lane & 15) * 8) ^ ((r & 7) << 4));  // conflict-free: 16 lanes span full 128B row
  }
  // ---- B: 4 gload_lds of 1KB, source pre-swizzled (m173) ----
  const unsigned short* srcB[4]; unsigned qB[4];
#pragma unroll
  for (int i = 0; i < 4; i++) {
    unsigned q = (unsigned)wid * 4096u + (unsigned)i * 1024u + (unsigned)lane * 16u;
    unsigned r = q >> 7, b = q & 127u;
    unsigned cb = b ^ ((r & 7u) << 4);          // inverse swizzle on source
    qB[i] = 16384u + q;
    srcB[i] = wb + (size_t)(colBase + (int)r) * F_DIM + (cb >> 1);
  }

  // swizzled ds_read byte offsets (relative to buffer base)
  int aOff[4][2], bOff[4][2];
#pragma unroll
  for (int m = 0; m < 4; m++) {
    int r = wr * 64 + m * 16 + (lane & 15);
    int sw = (r & 7) << 4;
#pragma unroll
    for (int ks = 0; ks < 2; ks++) {
      int kb = ks * 64 + ((lane >> 4) << 4);
      aOff[m][ks] = r * 128 + (kb ^ sw);
    }
  }
#pragma unroll
  for (int n = 0; n < 4; n++) {
    int r = wc * 64 + n * 16 + (lane & 15);
    int sw = (r & 7) << 4;
#pragma unroll
    for (int ks = 0; ks < 2; ks++) {
      int kb = ks * 64 + ((lane >> 4) << 4);
      bOff[n][ks] = 16384 + r * 128 + (kb ^ sw);
    }
  }

  f32x4 acc[4][4];
#pragma unroll
  for (int m = 0; m < 4; m++)
#pragma unroll
    for (int n = 0; n < 4; n++)
      acc[m][n] = (f32x4){0.f, 0.f, 0.f, 0.f};

  f32x4 aregA[8], aregB[8];   // two A-reg sets: load t+2 while t+1 in flight
#define LOADA(REG, KT) do { \
  _Pragma("unroll") \
  for (int i = 0; i < 8; i++) \
    REG[i] = *(const f32x4*)(aSrc + (size_t)i * 4 * F_DIM + (KT) * 64); \
} while (0)
#define WRITEA(BUF, REG) do { \
  _Pragma("unroll") \
  for (int i = 0; i < 8; i++) { \
    unsigned lo = ((unsigned)f2bf(REG[i][1]) << 16) | f2bf(REG[i][0]); \
    unsigned hi = ((unsigned)f2bf(REG[i][3]) << 16) | f2bf(REG[i][2]); \
    u32x2 v; v[0] = lo; v[1] = hi; \
    *(u32x2*)((BUF) + wOffA[i]) = v; \
  } \
} while (0)

  auto loadB = [&](unsigned char* buf, int kt) {
    const size_t koff = (size_t)kt * 64;
#pragma unroll
    for (int i = 0; i < 4; i++) gload16(srcB[i] + koff, buf + qB[i]);
  };
  auto compute = [&](const unsigned char* buf) {
#pragma unroll
    for (int ks = 0; ks < 2; ks++) {
      bf16x8 a0 = *(const bf16x8*)(buf + aOff[0][ks]);
      bf16x8 a1 = *(const bf16x8*)(buf + aOff[1][ks]);
      bf16x8 a2 = *(const bf16x8*)(buf + aOff[2][ks]);
      bf16x8 a3 = *(const bf16x8*)(buf + aOff[3][ks]);
      bf16x8 b0 = *(const bf16x8*)(buf + bOff[0][ks]);
      bf16x8 b1 = *(const bf16x8*)(buf + bOff[1][ks]);
      bf16x8 b2 = *(const bf16x8*)(buf + bOff[2][ks]);
      bf16x8 b3 = *(const bf16x8*)(buf + bOff[3][ks]);
      __builtin_amdgcn_s_setprio(1);
      acc[0][0] = __builtin_amdgcn_mfma_f32_16x16x32_bf16(a0, b0, acc[0][0], 0, 0, 0);
      acc[0][1] = __builtin_amdgcn_mfma_f32_16x16x32_bf16(a0, b1, acc[0][1], 0, 0, 0);
      acc[0][2] = __builtin_amdgcn_mfma_f32_16x16x32_bf16(a0, b2, acc[0][2], 0, 0, 0);
      acc[0][3] = __builtin_amdgcn_mfma_f32_16x16x32_bf16(a0, b3, acc[0][3], 0, 0, 0);
      acc[1][0] = __builtin_amdgcn_mfma_f32_16x16x32_bf16(a1, b0, acc[1][0], 0, 0, 0);
      acc[1][1] = __builtin_amdgcn_mfma_f32_16x16x32_bf16(a1, b1, acc[1][1], 0, 0, 0);
      acc[1][2] = __builtin_amdgcn_mfma_f32_16x16x32_bf16(a1, b2, acc[1][2], 0, 0, 0);
      acc[1][3] = __builtin_amdgcn_mfma_f32_16x16x32_bf16(a1, b3, acc[1][3], 0, 0, 0);
      acc[2][0] = __builtin_amdgcn_mfma_f32_16x16x32_bf16(a2, b0, acc[2][0], 0, 0, 0);
      acc[2][1] = __builtin_amdgcn_mfma_f32_16x16x32_bf16(a2, b1, acc[2][1], 0, 0, 0);
      acc[2][2] = __builtin_amdgcn_mfma_f32_16x16x32_bf16(a2, b2, acc[2][2], 0, 0, 0);
      acc[2][3] = __builtin_amdgcn_mfma_f32_16x16x32_bf16(a2, b3, acc[2][3], 0, 0, 0);
      acc[3][0] = __builtin_amdgcn_mfma_f32_16x16x32_bf16(a3, b0, acc[3][0], 0, 0, 0);
      acc[3][1] = __builtin_amdgcn_mfma_f32_16x16x32_bf16(a3, b1, acc[3][1], 0, 0, 0);
      acc[3][2] = __builtin_amdgcn_mfma_f32_16x16x32_bf16(a3, b2, acc[3][2], 0, 0, 0);
      acc[3][3] = __builtin_amdgcn_mfma_f32_16x16x32_bf16(a3, b3, acc[3][3], 0, 0, 0);
      __builtin_amdgcn_s_setprio(0);
    }
  };

  // ---- prologue: tile0 staged, A(1) in flight across first barrier ----
  LOADA(aregA, 0); SB0();
  loadB(buf0, 0);  SB0();
  WRITEA(buf0, aregA);          // compiler waits A(0) exactly (vmcnt(4))
  LOADA(aregB, 1); SB0();
  BAR8();                       // B(0) landed; A(1)'s 8 loads cross barrier
  // ---- main loop: one barrier per K-step; invariant at top: A(t+1) in flight ----
  for (int kt = 0; kt < 28; kt += 2) {
    // step kt: cur=buf0, aregB = A(kt+1) in flight
    loadB(buf1, kt + 1); SB0();
    LOADA(aregA, kt + 2); SB0();
    compute(buf0);
    WRITEA(buf1, aregB);        // waits A(kt+1) (vmcnt(12)), B+A(kt+2) in flight
    BAR8();                     // B(kt+1) landed; A(kt+2) crosses
    // step kt+1: cur=buf1, aregA = A(kt+2) in flight
    loadB(buf0, kt + 2); SB0();
    LOADA(aregB, kt + 3); SB0();
    compute(buf1);
    WRITEA(buf0, aregA);
    BAR8();
  }
  // peeled steps 28..31 (tiles bounded at 31)
  loadB(buf1, 29); SB0();
  LOADA(aregA, 30); SB0();
  compute(buf0);
  WRITEA(buf1, aregB);          // A(29)
  BAR8();
  loadB(buf0, 30); SB0();
  LOADA(aregB, 31); SB0();
  compute(buf1);
  WRITEA(buf0, aregA);          // A(30)
  BAR8();
  loadB(buf1, 31); SB0();
  compute(buf0);
  WRITEA(buf1, aregB);          // A(31)
  BAR0();                       // drain: B(31) landed
  compute(buf1);
  BARLG();                      // all LDS reads done before smem reuse

  // ---- epilogue: u -> LDS [128][132] (padded stride: <=2-way banks, free) ----
  float* uT = (float*)smem;
#pragma unroll
  for (int m = 0; m < 4; m++)
#pragma unroll
    for (int n = 0; n < 4; n++)
#pragma unroll
      for (int j = 0; j < 4; j++) {
        int row = wr * 64 + m * 16 + ((lane >> 4) << 2) + j;  // C/D layout
        int col = wc * 64 + n * 16 + (lane & 15);
        uT[row * 132 + col] = acc[m][n][j];
      }
  __syncthreads();
  const int capBase = bn * 8;
#pragma unroll
  for (int pp = 0; pp < 4; ++pp) {
    int pi = t + pp * 256;
    int row = pi & 127;
    int cl = __builtin_amdgcn_readfirstlane(pi >> 7);  // wave-uniform capsule
    const float* uu = uT + row * 132 + cl * 16;
    f32x4 u0 = *(const f32x4*)(uu + 0);
    f32x4 u1 = *(const f32x4*)(uu + 4);
    f32x4 u2 = *(const f32x4*)(uu + 8);
    f32x4 u3 = *(const f32x4*)(uu + 12);
    float ur[16];
#pragma unroll
    for (int j = 0; j < 4; j++) { ur[j] = u0[j]; ur[4+j] = u1[j]; ur[8+j] = u2[j]; ur[12+j] = u3[j]; }
    int cap = capBase + cl;
    const float* s = sigma + (size_t)cap * 256;   // wave-uniform -> s_loads
    float qf = 0.f;
#pragma unroll
    for (int dd = 0; dd < 16; ++dd) {
      float td = 0.f;
#pragma unroll
      for (int ee = 0; ee < 16; ++ee) td = fmaf(s[dd * 16 + ee], ur[ee], td);
      qf = fmaf(ur[dd], td, qf);
    }
    if (cap < C_DIM)
      out[(size_t)(rowBase + row) * C_DIM + cap] = sqrtf(fmaxf(qf, 0.f));
  }
}

extern "C" void kernel_launch(void* const* d_in, const int* in_sizes, int n_in,
                              void* d_out, int out_size, void* d_ws, size_t ws_size,
                              hipStream_t stream) {
  const float* x = (const float*)d_in[0];   // [4096][2048]
  const float* w = (const float*)d_in[1];   // [100][16][2048]
  float* out = (float*)d_out;               // [4096][100]

  unsigned short* wb = (unsigned short*)d_ws;              // 1664 rows bf16 = 6.8 MB
  float* sigma = (float*)(wb + (size_t)N_PAD * F_DIM);     // 100x256 f32 (+pad caps read-only)

  int nw8 = N_DIM * F_DIM / 8;              // 409600
  int npad8 = (N_PAD - N_DIM) * F_DIM / 8;  // 16384
  int grid = C_DIM + (nw8 + npad8 + 255) / 256;   // gram blocks first, then w-convert
  cvt_gram_kernel<<<grid, 256, 0, stream>>>(w, wb, sigma, nw8, npad8);
  gemm_caps_kernel<<<(B_DIM / 128) * (N_PAD / 128), 256, 0, stream>>>(x, wb, sigma, out);
}

// Round 8
// 56.325 us; speedup vs baseline: 1.1844x; 1.1632x over previous
//
#include <hip/hip_runtime.h>
#include <hip/hip_bf16.h>
#include <math.h>

#define F_DIM 2048
#define B_DIM 4096
#define C_DIM 100
#define D_DIM 16
#define N_DIM (C_DIM*D_DIM)   // 1600
#define N_PAD 1664            // 13 tiles of 128
#define RIDGE_EPS 1e-4f

typedef __attribute__((ext_vector_type(8))) short bf16x8;
typedef __attribute__((ext_vector_type(4))) float f32x4;

__device__ __forceinline__ void gload16(const void* g, void* l) {
  __builtin_amdgcn_global_load_lds(
      (const __attribute__((address_space(1))) void*)g,
      (__attribute__((address_space(3))) void*)l,
      16, 0, 0);
}

// counted-vmcnt barrier (T4): never drain to 0 in steady state.
#define VM_BAR(N) asm volatile("s_waitcnt vmcnt(" #N ")\n\ts_barrier" ::: "memory")
#define LGKM_BAR() asm volatile("s_waitcnt lgkmcnt(0)\n\ts_barrier" ::: "memory")

__device__ __forceinline__ unsigned short f2bf(float f) {
  unsigned u = __float_as_uint(f);
  u += 0x7FFFu + ((u >> 16) & 1u);
  return (unsigned short)(u >> 16);
}

// ---- fused: blocks 0..99 = per-capsule Gram+inverse (reads fp32 w directly);
//      blocks 100.. = fp32->bf16 convert of x and w + zero-pad of wb rows ----
__global__ __launch_bounds__(256) void cvt_gram_kernel(
    const float* __restrict__ x, const float* __restrict__ w,
    unsigned short* __restrict__ xb, unsigned short* __restrict__ wb,
    float* __restrict__ sigma, int nx8, int nw8, int npad8) {
  __shared__ float part[4][64][4];
  __shared__ float G[16][17];
  __shared__ float IV[16][17];
  int t = threadIdx.x;
  if (blockIdx.x < C_DIM) {
    // ---------------- gram + Gauss-Jordan inverse ----------------
    int c = blockIdx.x;
    int lane = t & 63, wid = t >> 6;
    const float* src = w + (size_t)c * (D_DIM * F_DIM)
                         + (size_t)(lane & 15) * F_DIM + ((lane >> 4) * 8) + wid * 512;
    f32x4 g = {0.f, 0.f, 0.f, 0.f};
#pragma unroll
    for (int kt = 0; kt < 16; ++kt) {
      float4 v0 = *(const float4*)(src + kt * 32);
      float4 v1 = *(const float4*)(src + kt * 32 + 4);
      bf16x8 f;
      f[0] = (short)f2bf(v0.x); f[1] = (short)f2bf(v0.y);
      f[2] = (short)f2bf(v0.z); f[3] = (short)f2bf(v0.w);
      f[4] = (short)f2bf(v1.x); f[5] = (short)f2bf(v1.y);
      f[6] = (short)f2bf(v1.z); f[7] = (short)f2bf(v1.w);
      g = __builtin_amdgcn_mfma_f32_16x16x32_bf16(f, f, g, 0, 0, 0);
    }
#pragma unroll
    for (int j = 0; j < 4; j++) part[wid][lane][j] = g[j];
    int d = t >> 4, e = t & 15;
    IV[d][e] = (d == e) ? 1.f : 0.f;
    __syncthreads();
    if (t < 64) {
      int col = t & 15;
#pragma unroll
      for (int j = 0; j < 4; j++) {
        int row = (t >> 4) * 4 + j;   // C/D layout; G symmetric so transpose harmless
        float s4 = part[0][t][j] + part[1][t][j] + part[2][t][j] + part[3][t][j];
        G[row][col] = s4 + (row == col ? RIDGE_EPS : 0.f);
      }
    }
    __syncthreads();
    // Gauss-Jordan, no pivoting (SPD, diag ~1/3, ridge-regularized); t owns (d,e)
    for (int k = 0; k < 16; k++) {
      float piv = G[k][k];
      float gke = G[k][e];
      float ike = IV[k][e];
      float f   = G[d][k];
      float gde = G[d][e];
      float ide = IV[d][e];
      __syncthreads();
      if (d == k) {
        G[k][e]  = gke / piv;
        IV[k][e] = ike / piv;
      } else {
        G[d][e]  = gde - f * gke / piv;
        IV[d][e] = ide - f * ike / piv;
      }
      __syncthreads();
    }
    sigma[(size_t)c * 256 + t] = IV[d][e];
    return;
  }
  // ---------------- converts ----------------
  int i = (blockIdx.x - C_DIM) * 256 + t;
  const float* in; unsigned short* outp; int idx;
  if (i < nx8) { in = x; outp = xb; idx = i; }
  else {
    idx = i - nx8;
    if (idx >= nw8) {
      int idx3 = idx - nw8;
      if (idx3 < npad8) {  // zero-fill wb pad rows 1600..1663
        uint4 z = {0, 0, 0, 0};
        *((uint4*)(wb + (size_t)N_DIM * F_DIM) + idx3) = z;
      }
      return;
    }
    in = w; outp = wb;
  }
  const float4* p = (const float4*)in + (size_t)idx * 2;
  float4 a = p[0], b = p[1];
  float v[8] = {a.x, a.y, a.z, a.w, b.x, b.y, b.z, b.w};
  union { unsigned short u16[8]; uint4 u4; } r;
#pragma unroll
  for (int j = 0; j < 8; j++) r.u16[j] = f2bf(v[j]);
  *((uint4*)outp + idx) = r.u4;
}

// ------------- fused bf16 MFMA GEMM (u = x W^T) + sqrt(u^T S u) -------------
// tile BM=128 x BN=128 (8 capsules), BK=64, 4 waves 2x2, each 64x64 (4x4 frags)
// Double-buffered LDS, counted-vmcnt pipeline:
//   { stage(next,8); vmcnt(8)+bar; ds_read+MFMA(cur); lgkm0+bar }
// Epilogue: padded uT[128][132] (stride%32==4 -> <=2 lanes/bank, conflict-free;
// validated in r7: SQ_LDS_BANK_CONFLICT == 0).
__global__ __launch_bounds__(256) void gemm_caps_kernel(
    const unsigned short* __restrict__ xb,   // [4096][2048] bf16
    const unsigned short* __restrict__ wb,   // [1664][2048] bf16 (rows>=1600 zero)
    const float* __restrict__ sigma,         // [100][16][16]
    float* __restrict__ out)                 // [4096][100]
{
  __shared__ __align__(16) unsigned char smem[67584];
  const int t = threadIdx.x;
  const int lane = t & 63;
  const int wid = t >> 6;
  const int wr = wid >> 1, wc = wid & 1;    // 2x2 wave grid
  // bijective XCD swizzle: 416 blocks = 8 XCDs x 52
  const int bid = blockIdx.x;
  const int swz = (bid & 7) * 52 + (bid >> 3);
  const int bn = swz % 13;          // 13 consecutive share the A panel
  const int bm = swz / 13;
  const int rowBase = bm * 128;
  const int colBase = bn * 128;

  unsigned char* buf0 = smem;
  unsigned char* buf1 = smem + 32768;
  // per-buffer: sA = buf (128x64 bf16 = 16KB), sB = buf+16384 (128x64 = 16KB)

  // staging: per wave 4 A + 4 B gloads of 1KB (64 lanes x 16B)
  const unsigned short* srcA[4]; unsigned qA[4];
  const unsigned short* srcB[4]; unsigned qB[4];
#pragma unroll
  for (int i = 0; i < 4; i++) {
    unsigned q = (unsigned)wid * 4096u + (unsigned)i * 1024u + (unsigned)lane * 16u;
    unsigned r = q >> 7, b = q & 127u;
    unsigned cb = b ^ ((r & 7u) << 4);          // inverse swizzle on source
    qA[i] = q;
    srcA[i] = xb + (size_t)(rowBase + (int)r) * F_DIM + (cb >> 1);
    qB[i] = 16384u + q;
    srcB[i] = wb + (size_t)(colBase + (int)r) * F_DIM + (cb >> 1);
  }

  // swizzled ds_read byte offsets (relative to buffer base)
  int aOff[4][2], bOff[4][2];
#pragma unroll
  for (int m = 0; m < 4; m++) {
    int r = wr * 64 + m * 16 + (lane & 15);
    int sw = (r & 7) << 4;
#pragma unroll
    for (int ks = 0; ks < 2; ks++) {
      int kb = ks * 64 + ((lane >> 4) << 4);
      aOff[m][ks] = r * 128 + (kb ^ sw);
    }
  }
#pragma unroll
  for (int n = 0; n < 4; n++) {
    int r = wc * 64 + n * 16 + (lane & 15);
    int sw = (r & 7) << 4;
#pragma unroll
    for (int ks = 0; ks < 2; ks++) {
      int kb = ks * 64 + ((lane >> 4) << 4);
      bOff[n][ks] = 16384 + r * 128 + (kb ^ sw);
    }
  }

  f32x4 acc[4][4];
#pragma unroll
  for (int m = 0; m < 4; m++)
#pragma unroll
    for (int n = 0; n < 4; n++)
      acc[m][n] = (f32x4){0.f, 0.f, 0.f, 0.f};

  auto stage = [&](unsigned char* buf, int kt) {
    const size_t koff = (size_t)kt * 64;
#pragma unroll
    for (int i = 0; i < 4; i++) gload16(srcA[i] + koff, buf + qA[i]);
#pragma unroll
    for (int i = 0; i < 4; i++) gload16(srcB[i] + koff, buf + qB[i]);
  };
  auto compute = [&](const unsigned char* buf) {
#pragma unroll
    for (int ks = 0; ks < 2; ks++) {
      bf16x8 a0 = *(const bf16x8*)(buf + aOff[0][ks]);
      bf16x8 a1 = *(const bf16x8*)(buf + aOff[1][ks]);
      bf16x8 a2 = *(const bf16x8*)(buf + aOff[2][ks]);
      bf16x8 a3 = *(const bf16x8*)(buf + aOff[3][ks]);
      bf16x8 b0 = *(const bf16x8*)(buf + bOff[0][ks]);
      bf16x8 b1 = *(const bf16x8*)(buf + bOff[1][ks]);
      bf16x8 b2 = *(const bf16x8*)(buf + bOff[2][ks]);
      bf16x8 b3 = *(const bf16x8*)(buf + bOff[3][ks]);
      __builtin_amdgcn_s_setprio(1);
      acc[0][0] = __builtin_amdgcn_mfma_f32_16x16x32_bf16(a0, b0, acc[0][0], 0, 0, 0);
      acc[0][1] = __builtin_amdgcn_mfma_f32_16x16x32_bf16(a0, b1, acc[0][1], 0, 0, 0);
      acc[0][2] = __builtin_amdgcn_mfma_f32_16x16x32_bf16(a0, b2, acc[0][2], 0, 0, 0);
      acc[0][3] = __builtin_amdgcn_mfma_f32_16x16x32_bf16(a0, b3, acc[0][3], 0, 0, 0);
      acc[1][0] = __builtin_amdgcn_mfma_f32_16x16x32_bf16(a1, b0, acc[1][0], 0, 0, 0);
      acc[1][1] = __builtin_amdgcn_mfma_f32_16x16x32_bf16(a1, b1, acc[1][1], 0, 0, 0);
      acc[1][2] = __builtin_amdgcn_mfma_f32_16x16x32_bf16(a1, b2, acc[1][2], 0, 0, 0);
      acc[1][3] = __builtin_amdgcn_mfma_f32_16x16x32_bf16(a1, b3, acc[1][3], 0, 0, 0);
      acc[2][0] = __builtin_amdgcn_mfma_f32_16x16x32_bf16(a2, b0, acc[2][0], 0, 0, 0);
      acc[2][1] = __builtin_amdgcn_mfma_f32_16x16x32_bf16(a2, b1, acc[2][1], 0, 0, 0);
      acc[2][2] = __builtin_amdgcn_mfma_f32_16x16x32_bf16(a2, b2, acc[2][2], 0, 0, 0);
      acc[2][3] = __builtin_amdgcn_mfma_f32_16x16x32_bf16(a2, b3, acc[2][3], 0, 0, 0);
      acc[3][0] = __builtin_amdgcn_mfma_f32_16x16x32_bf16(a3, b0, acc[3][0], 0, 0, 0);
      acc[3][1] = __builtin_amdgcn_mfma_f32_16x16x32_bf16(a3, b1, acc[3][1], 0, 0, 0);
      acc[3][2] = __builtin_amdgcn_mfma_f32_16x16x32_bf16(a3, b2, acc[3][2], 0, 0, 0);
      acc[3][3] = __builtin_amdgcn_mfma_f32_16x16x32_bf16(a3, b3, acc[3][3], 0, 0, 0);
      __builtin_amdgcn_s_setprio(0);
    }
  };

  // counted-vmcnt pipeline over 32 K-steps (each wave: exactly 8 loads/K-step)
  stage(buf0, 0);
  for (int kt = 0; kt < 30; kt += 2) {
    stage(buf1, kt + 1);
    VM_BAR(8);
    compute(buf0);
    LGKM_BAR();
    stage(buf0, kt + 2);
    VM_BAR(8);
    compute(buf1);
    LGKM_BAR();
  }
  stage(buf1, 31);
  VM_BAR(8);
  compute(buf0);
  LGKM_BAR();
  VM_BAR(0);
  compute(buf1);
  LGKM_BAR();   // all LDS reads done before smem reuse

  // ---- epilogue: u -> LDS [128][132] (padded stride: <=2-way banks, free) ----
  float* uT = (float*)smem;
#pragma unroll
  for (int m = 0; m < 4; m++)
#pragma unroll
    for (int n = 0; n < 4; n++)
#pragma unroll
      for (int j = 0; j < 4; j++) {
        int row = wr * 64 + m * 16 + ((lane >> 4) << 2) + j;  // C/D layout
        int col = wc * 64 + n * 16 + (lane & 15);
        uT[row * 132 + col] = acc[m][n][j];
      }
  __syncthreads();
  const int capBase = bn * 8;
#pragma unroll
  for (int pp = 0; pp < 4; ++pp) {
    int pi = t + pp * 256;
    int row = pi & 127;
    int cl = __builtin_amdgcn_readfirstlane(pi >> 7);  // wave-uniform capsule
    const float* uu = uT + row * 132 + cl * 16;
    f32x4 u0 = *(const f32x4*)(uu + 0);
    f32x4 u1 = *(const f32x4*)(uu + 4);
    f32x4 u2 = *(const f32x4*)(uu + 8);
    f32x4 u3 = *(const f32x4*)(uu + 12);
    float ur[16];
#pragma unroll
    for (int j = 0; j < 4; j++) { ur[j] = u0[j]; ur[4+j] = u1[j]; ur[8+j] = u2[j]; ur[12+j] = u3[j]; }
    int cap = capBase + cl;
    const float* s = sigma + (size_t)cap * 256;   // wave-uniform -> s_loads
    float qf = 0.f;
#pragma unroll
    for (int dd = 0; dd < 16; ++dd) {
      float td = 0.f;
#pragma unroll
      for (int ee = 0; ee < 16; ++ee) td = fmaf(s[dd * 16 + ee], ur[ee], td);
      qf = fmaf(ur[dd], td, qf);
    }
    if (cap < C_DIM)
      out[(size_t)(rowBase + row) * C_DIM + cap] = sqrtf(fmaxf(qf, 0.f));
  }
}

extern "C" void kernel_launch(void* const* d_in, const int* in_sizes, int n_in,
                              void* d_out, int out_size, void* d_ws, size_t ws_size,
                              hipStream_t stream) {
  const float* x = (const float*)d_in[0];   // [4096][2048]
  const float* w = (const float*)d_in[1];   // [100][16][2048]
  float* out = (float*)d_out;               // [4096][100]

  unsigned short* xb = (unsigned short*)d_ws;              // 16 MB
  unsigned short* wb = xb + (size_t)B_DIM * F_DIM;         // 1664 rows = 6.8 MB
  float* sigma = (float*)(wb + (size_t)N_PAD * F_DIM);     // 100x256 f32 (+pad caps read-only)

  int nx8 = B_DIM * F_DIM / 8;              // 1048576
  int nw8 = N_DIM * F_DIM / 8;              // 409600
  int npad8 = (N_PAD - N_DIM) * F_DIM / 8;  // 16384
  int nconv = nx8 + nw8 + npad8;
  int grid = C_DIM + (nconv + 255) / 256;   // gram blocks first, then converts
  cvt_gram_kernel<<<grid, 256, 0, stream>>>(x, w, xb, wb, sigma, nx8, nw8, npad8);
  gemm_caps_kernel<<<(B_DIM / 128) * (N_PAD / 128), 256, 0, stream>>>(xb, wb, sigma, out);
}

// Round 9
// 51.533 us; speedup vs baseline: 1.2946x; 1.0930x over previous
//
#include <hip/hip_runtime.h>
#include <hip/hip_bf16.h>
#include <math.h>

#define F_DIM 2048
#define B_DIM 4096
#define C_DIM 100
#define D_DIM 16
#define N_DIM (C_DIM*D_DIM)   // 1600
#define N_PAD 1664            // 13 tiles of 128
#define RIDGE_EPS 1e-4f

typedef __attribute__((ext_vector_type(8))) short bf16x8;
typedef __attribute__((ext_vector_type(4))) float f32x4;

__device__ __forceinline__ void gload16(const void* g, void* l) {
  __builtin_amdgcn_global_load_lds(
      (const __attribute__((address_space(1))) void*)g,
      (__attribute__((address_space(3))) void*)l,
      16, 0, 0);
}

// counted-vmcnt barrier (T4): never drain to 0 in steady state.
#define VM_BAR(N) asm volatile("s_waitcnt vmcnt(" #N ")\n\ts_barrier" ::: "memory")
#define LGKM_BAR() asm volatile("s_waitcnt lgkmcnt(0)\n\ts_barrier" ::: "memory")

__device__ __forceinline__ unsigned short f2bf(float f) {
  unsigned u = __float_as_uint(f);
  u += 0x7FFFu + ((u >> 16) & 1u);
  return (unsigned short)(u >> 16);
}

// ---- fused: blocks 0..99 = per-capsule Gram+inverse (reads fp32 w directly);
//      blocks 100.. = fp32->bf16 convert of x and w + zero-pad of wb rows ----
__global__ __launch_bounds__(256) void cvt_gram_kernel(
    const float* __restrict__ x, const float* __restrict__ w,
    unsigned short* __restrict__ xb, unsigned short* __restrict__ wb,
    float* __restrict__ sigma, int nx8, int nw8, int npad8) {
  __shared__ float part[4][64][4];
  __shared__ float G[16][17];
  __shared__ float IV[16][17];
  int t = threadIdx.x;
  if (blockIdx.x < C_DIM) {
    // ---------------- gram + Gauss-Jordan inverse ----------------
    int c = blockIdx.x;
    int lane = t & 63, wid = t >> 6;
    const float* src = w + (size_t)c * (D_DIM * F_DIM)
                         + (size_t)(lane & 15) * F_DIM + ((lane >> 4) * 8) + wid * 512;
    f32x4 g = {0.f, 0.f, 0.f, 0.f};
#pragma unroll
    for (int kt = 0; kt < 16; ++kt) {
      float4 v0 = *(const float4*)(src + kt * 32);
      float4 v1 = *(const float4*)(src + kt * 32 + 4);
      bf16x8 f;
      f[0] = (short)f2bf(v0.x); f[1] = (short)f2bf(v0.y);
      f[2] = (short)f2bf(v0.z); f[3] = (short)f2bf(v0.w);
      f[4] = (short)f2bf(v1.x); f[5] = (short)f2bf(v1.y);
      f[6] = (short)f2bf(v1.z); f[7] = (short)f2bf(v1.w);
      g = __builtin_amdgcn_mfma_f32_16x16x32_bf16(f, f, g, 0, 0, 0);
    }
#pragma unroll
    for (int j = 0; j < 4; j++) part[wid][lane][j] = g[j];
    int d = t >> 4, e = t & 15;
    IV[d][e] = (d == e) ? 1.f : 0.f;
    __syncthreads();
    if (t < 64) {
      int col = t & 15;
#pragma unroll
      for (int j = 0; j < 4; j++) {
        int row = (t >> 4) * 4 + j;   // C/D layout; G symmetric so transpose harmless
        float s4 = part[0][t][j] + part[1][t][j] + part[2][t][j] + part[3][t][j];
        G[row][col] = s4 + (row == col ? RIDGE_EPS : 0.f);
      }
    }
    __syncthreads();
    // Gauss-Jordan, no pivoting (SPD, diag ~1/3, ridge-regularized); t owns (d,e)
    for (int k = 0; k < 16; k++) {
      float piv = G[k][k];
      float gke = G[k][e];
      float ike = IV[k][e];
      float f   = G[d][k];
      float gde = G[d][e];
      float ide = IV[d][e];
      __syncthreads();
      if (d == k) {
        G[k][e]  = gke / piv;
        IV[k][e] = ike / piv;
      } else {
        G[d][e]  = gde - f * gke / piv;
        IV[d][e] = ide - f * ike / piv;
      }
      __syncthreads();
    }
    sigma[(size_t)c * 256 + t] = IV[d][e];
    return;
  }
  // ---------------- converts ----------------
  int i = (blockIdx.x - C_DIM) * 256 + t;
  const float* in; unsigned short* outp; int idx;
  if (i < nx8) { in = x; outp = xb; idx = i; }
  else {
    idx = i - nx8;
    if (idx >= nw8) {
      int idx3 = idx - nw8;
      if (idx3 < npad8) {  // zero-fill wb pad rows 1600..1663
        uint4 z = {0, 0, 0, 0};
        *((uint4*)(wb + (size_t)N_DIM * F_DIM) + idx3) = z;
      }
      return;
    }
    in = w; outp = wb;
  }
  const float4* p = (const float4*)in + (size_t)idx * 2;
  float4 a = p[0], b = p[1];
  float v[8] = {a.x, a.y, a.z, a.w, b.x, b.y, b.z, b.w};
  union { unsigned short u16[8]; uint4 u4; } r;
#pragma unroll
  for (int j = 0; j < 8; j++) r.u16[j] = f2bf(v[j]);
  *((uint4*)outp + idx) = r.u4;
}

// ------------- fused bf16 MFMA GEMM (u = x W^T) + sqrt(u^T S u) -------------
// tile BM=128 x BN=128 (8 capsules), BK=64, 8 waves in 2x4 grid, wave=64x32
// (4m x 2n frags, 16 MFMA/step/wave). 512 threads doubles waves/CU vs the
// 4-wave variant (grid-bound occupancy 6.5 -> 13 waves/CU) to hide the
// barrier/latency stalls (m114 mechanism). Double-buffered LDS, counted
// vmcnt(4) pipeline (each wave issues exactly 4 gloads/K-step).
__global__ __launch_bounds__(512) void gemm_caps_kernel(
    const unsigned short* __restrict__ xb,   // [4096][2048] bf16
    const unsigned short* __restrict__ wb,   // [1664][2048] bf16 (rows>=1600 zero)
    const float* __restrict__ sigma,         // [100][16][16]
    float* __restrict__ out)                 // [4096][100]
{
  __shared__ __align__(16) unsigned char smem[67584];
  const int t = threadIdx.x;
  const int lane = t & 63;
  const int wid = t >> 6;
  const int wr = wid >> 2, wc = wid & 3;    // 2x4 wave grid
  // bijective XCD swizzle: 416 blocks = 8 XCDs x 52
  const int bid = blockIdx.x;
  const int swz = (bid & 7) * 52 + (bid >> 3);
  const int bn = swz % 13;          // 13 consecutive share the A panel
  const int bm = swz / 13;
  const int rowBase = bm * 128;
  const int colBase = bn * 128;

  unsigned char* buf0 = smem;
  unsigned char* buf1 = smem + 32768;
  // per-buffer: sA = buf (128x64 bf16 = 16KB), sB = buf+16384 (128x64 = 16KB)

  // staging: per wave 2 A + 2 B gloads of 1KB (64 lanes x 16B); 8 waves cover 32KB
  const unsigned short* srcA[2]; unsigned qA[2];
  const unsigned short* srcB[2]; unsigned qB[2];
#pragma unroll
  for (int i = 0; i < 2; i++) {
    unsigned q = (unsigned)wid * 1024u + (unsigned)i * 8192u + (unsigned)lane * 16u;
    unsigned r = q >> 7, b = q & 127u;
    unsigned cb = b ^ ((r & 7u) << 4);          // inverse swizzle on source
    qA[i] = q;
    srcA[i] = xb + (size_t)(rowBase + (int)r) * F_DIM + (cb >> 1);
    qB[i] = 16384u + q;
    srcB[i] = wb + (size_t)(colBase + (int)r) * F_DIM + (cb >> 1);
  }

  // swizzled ds_read byte offsets (relative to buffer base)
  int aOff[4][2], bOff[2][2];
#pragma unroll
  for (int m = 0; m < 4; m++) {
    int r = wr * 64 + m * 16 + (lane & 15);
    int sw = (r & 7) << 4;
#pragma unroll
    for (int ks = 0; ks < 2; ks++) {
      int kb = ks * 64 + ((lane >> 4) << 4);
      aOff[m][ks] = r * 128 + (kb ^ sw);
    }
  }
#pragma unroll
  for (int n = 0; n < 2; n++) {
    int r = wc * 32 + n * 16 + (lane & 15);
    int sw = (r & 7) << 4;
#pragma unroll
    for (int ks = 0; ks < 2; ks++) {
      int kb = ks * 64 + ((lane >> 4) << 4);
      bOff[n][ks] = 16384 + r * 128 + (kb ^ sw);
    }
  }

  f32x4 acc[4][2];
#pragma unroll
  for (int m = 0; m < 4; m++)
#pragma unroll
    for (int n = 0; n < 2; n++)
      acc[m][n] = (f32x4){0.f, 0.f, 0.f, 0.f};

  auto stage = [&](unsigned char* buf, int kt) {
    const size_t koff = (size_t)kt * 64;
#pragma unroll
    for (int i = 0; i < 2; i++) gload16(srcA[i] + koff, buf + qA[i]);
#pragma unroll
    for (int i = 0; i < 2; i++) gload16(srcB[i] + koff, buf + qB[i]);
  };
  auto compute = [&](const unsigned char* buf) {
#pragma unroll
    for (int ks = 0; ks < 2; ks++) {
      bf16x8 a0 = *(const bf16x8*)(buf + aOff[0][ks]);
      bf16x8 a1 = *(const bf16x8*)(buf + aOff[1][ks]);
      bf16x8 a2 = *(const bf16x8*)(buf + aOff[2][ks]);
      bf16x8 a3 = *(const bf16x8*)(buf + aOff[3][ks]);
      bf16x8 b0 = *(const bf16x8*)(buf + bOff[0][ks]);
      bf16x8 b1 = *(const bf16x8*)(buf + bOff[1][ks]);
      __builtin_amdgcn_s_setprio(1);
      acc[0][0] = __builtin_amdgcn_mfma_f32_16x16x32_bf16(a0, b0, acc[0][0], 0, 0, 0);
      acc[0][1] = __builtin_amdgcn_mfma_f32_16x16x32_bf16(a0, b1, acc[0][1], 0, 0, 0);
      acc[1][0] = __builtin_amdgcn_mfma_f32_16x16x32_bf16(a1, b0, acc[1][0], 0, 0, 0);
      acc[1][1] = __builtin_amdgcn_mfma_f32_16x16x32_bf16(a1, b1, acc[1][1], 0, 0, 0);
      acc[2][0] = __builtin_amdgcn_mfma_f32_16x16x32_bf16(a2, b0, acc[2][0], 0, 0, 0);
      acc[2][1] = __builtin_amdgcn_mfma_f32_16x16x32_bf16(a2, b1, acc[2][1], 0, 0, 0);
      acc[3][0] = __builtin_amdgcn_mfma_f32_16x16x32_bf16(a3, b0, acc[3][0], 0, 0, 0);
      acc[3][1] = __builtin_amdgcn_mfma_f32_16x16x32_bf16(a3, b1, acc[3][1], 0, 0, 0);
      __builtin_amdgcn_s_setprio(0);
    }
  };

  // counted-vmcnt pipeline over 32 K-steps (each wave: exactly 4 loads/K-step)
  stage(buf0, 0);
  for (int kt = 0; kt < 30; kt += 2) {
    stage(buf1, kt + 1);
    VM_BAR(4);
    compute(buf0);
    LGKM_BAR();
    stage(buf0, kt + 2);
    VM_BAR(4);
    compute(buf1);
    LGKM_BAR();
  }
  stage(buf1, 31);
  VM_BAR(4);
  compute(buf0);
  LGKM_BAR();
  VM_BAR(0);
  compute(buf1);
  LGKM_BAR();   // all LDS reads done before smem reuse

  // ---- epilogue: u -> LDS [128][132] (padded stride: conflict-free, r8-validated) ----
  float* uT = (float*)smem;
#pragma unroll
  for (int m = 0; m < 4; m++)
#pragma unroll
    for (int n = 0; n < 2; n++)
#pragma unroll
      for (int j = 0; j < 4; j++) {
        int row = wr * 64 + m * 16 + ((lane >> 4) << 2) + j;  // C/D layout
        int col = wc * 32 + n * 16 + (lane & 15);
        uT[row * 132 + col] = acc[m][n][j];
      }
  __syncthreads();
  const int capBase = bn * 8;
#pragma unroll
  for (int pp = 0; pp < 2; ++pp) {
    int pi = t + pp * 512;
    int row = pi & 127;
    int cl = __builtin_amdgcn_readfirstlane(pi >> 7);  // wave-uniform capsule
    const float* uu = uT + row * 132 + cl * 16;
    f32x4 u0 = *(const f32x4*)(uu + 0);
    f32x4 u1 = *(const f32x4*)(uu + 4);
    f32x4 u2 = *(const f32x4*)(uu + 8);
    f32x4 u3 = *(const f32x4*)(uu + 12);
    float ur[16];
#pragma unroll
    for (int j = 0; j < 4; j++) { ur[j] = u0[j]; ur[4+j] = u1[j]; ur[8+j] = u2[j]; ur[12+j] = u3[j]; }
    int cap = capBase + cl;
    const float* s = sigma + (size_t)cap * 256;   // wave-uniform -> s_loads
    float qf = 0.f;
#pragma unroll
    for (int dd = 0; dd < 16; ++dd) {
      float td = 0.f;
#pragma unroll
      for (int ee = 0; ee < 16; ++ee) td = fmaf(s[dd * 16 + ee], ur[ee], td);
      qf = fmaf(ur[dd], td, qf);
    }
    if (cap < C_DIM)
      out[(size_t)(rowBase + row) * C_DIM + cap] = sqrtf(fmaxf(qf, 0.f));
  }
}

extern "C" void kernel_launch(void* const* d_in, const int* in_sizes, int n_in,
                              void* d_out, int out_size, void* d_ws, size_t ws_size,
                              hipStream_t stream) {
  const float* x = (const float*)d_in[0];   // [4096][2048]
  const float* w = (const float*)d_in[1];   // [100][16][2048]
  float* out = (float*)d_out;               // [4096][100]

  unsigned short* xb = (unsigned short*)d_ws;              // 16 MB
  unsigned short* wb = xb + (size_t)B_DIM * F_DIM;         // 1664 rows = 6.8 MB
  float* sigma = (float*)(wb + (size_t)N_PAD * F_DIM);     // 100x256 f32 (+pad caps read-only)

  int nx8 = B_DIM * F_DIM / 8;              // 1048576
  int nw8 = N_DIM * F_DIM / 8;              // 409600
  int npad8 = (N_PAD - N_DIM) * F_DIM / 8;  // 16384
  int nconv = nx8 + nw8 + npad8;
  int grid = C_DIM + (nconv + 255) / 256;   // gram blocks first, then converts
  cvt_gram_kernel<<<grid, 256, 0, stream>>>(x, w, xb, wb, sigma, nx8, nw8, npad8);
  gemm_caps_kernel<<<(B_DIM / 128) * (N_PAD / 128), 512, 0, stream>>>(xb, wb, sigma, out);
}